// Round 6
// baseline (3049.771 us; speedup 1.0000x reference)
//
#include <hip/hip_runtime.h>

#define BB 32
#define TT 64
#define NQl 128
#define HD 128
#define CPAD 524   // sC row stride (floats)
#define HPAD 132   // padded row stride for fp32 [32][128] tiles

typedef _Float16 f16x8 __attribute__((ext_vector_type(8)));
typedef float f32x16 __attribute__((ext_vector_type(16)));
typedef float f32x4 __attribute__((ext_vector_type(4)));

__device__ __forceinline__ float sigmoidf_(float x) {
  return __builtin_amdgcn_rcpf(1.f + __expf(-x));
}
__device__ __forceinline__ float tanhf_(float x) {
  float a = fminf(fabsf(x), 15.f);
  float e = __expf(-2.f * a);
  float t = (1.f - e) * __builtin_amdgcn_rcpf(1.f + e);
  return copysignf(t, x);
}
__device__ __forceinline__ float dot4_(f32x4 a, f32x4 b) {
  return a[0] * b[0] + a[1] * b[1] + a[2] * b[2] + a[3] * b[3];
}
__device__ __forceinline__ f16x8 pack_frag_h(f32x4 a, f32x4 b) {
  f16x8 o;
  o[0] = (_Float16)a[0]; o[1] = (_Float16)a[1];
  o[2] = (_Float16)a[2]; o[3] = (_Float16)a[3];
  o[4] = (_Float16)b[0]; o[5] = (_Float16)b[1];
  o[6] = (_Float16)b[2]; o[7] = (_Float16)b[3];
  return o;
}
__device__ __forceinline__ uint4 pack8_h(const float v[8]) {
  union { f16x8 h; uint4 u; } c;
#pragma unroll
  for (int i = 0; i < 8; ++i) c.h[i] = (_Float16)v[i];
  return c.u;
}

// ---- agent-coherent (sc1: coherence point, cross-XCD) wide loads/stores ----
__device__ __forceinline__ void issue_load32_cc(const float* p, f32x4& a, f32x4& b) {
  asm volatile(
      "global_load_dwordx4 %0, %2, off sc1\n\t"
      "global_load_dwordx4 %1, %2, off offset:16 sc1"
      : "=&v"(a), "=&v"(b) : "v"(p) : "memory");
}
__device__ __forceinline__ void wait_vm0_2(f32x4& a, f32x4& b) {
  asm volatile("s_waitcnt vmcnt(0)" : "+v"(a), "+v"(b) :: "memory");
  __builtin_amdgcn_sched_barrier(0);
}
__device__ __forceinline__ void store32_cc(float* p, f32x4 a, f32x4 b) {
  asm volatile(
      "global_store_dwordx4 %0, %1, off sc1\n\t"
      "global_store_dwordx4 %0, %2, off offset:16 sc1"
      :: "v"(p), "v"(a), "v"(b) : "memory");
}

// RMW-based flag ops: always execute at the coherence point (no stale-cache path)
__device__ __forceinline__ int flag_read_rmw(int* p) {
  return __hip_atomic_fetch_add(p, 0, __ATOMIC_RELAXED, __HIP_MEMORY_SCOPE_AGENT);
}
__device__ __forceinline__ void flag_add1(int* p) {
  __hip_atomic_fetch_add(p, 1, __ATOMIC_RELAXED, __HIP_MEMORY_SCOPE_AGENT);
}

// fp16 single-product MFMA chain over NS K-slots starting at S0 -> sC[:, OUTCOL]
#define CHAIN(NS, S0, FR, BIASV, OUTCOL)                                        \
  {                                                                             \
    f32x16 acc;                                                                 \
    _Pragma("unroll")                                                           \
    for (int i = 0; i < 16; ++i) acc[i] = (BIASV);                              \
    _Pragma("unroll")                                                           \
    for (int ks = 0; ks < (NS); ++ks) {                                         \
      unsigned int off = ((unsigned int)(((S0) + ks) * 32 + (lhi << 4))) ^ swz; \
      f16x8 av = *(const f16x8*)(smA + rowbase + off);                          \
      acc = __builtin_amdgcn_mfma_f32_32x32x16_f16(av, FR[ks], acc, 0, 0, 0);   \
    }                                                                           \
    _Pragma("unroll")                                                           \
    for (int rg = 0; rg < 16; ++rg) {                                           \
      int br = (rg & 3) + 8 * (rg >> 2) + 4 * lhi;                              \
      sC[br * CPAD + (OUTCOL)] = acc[rg];                                       \
    }                                                                           \
  }

// One workgroup (512 threads = 8 waves) per time step t.
// Wavefront pipeline: step (t,n) consumes flag-counter(t-1,n)==8; depth T+NQ-1.
__global__ void __launch_bounds__(512, 2) gkt_wavefront(
    const int* __restrict__ qp, const int* __restrict__ rp_,
    const float* __restrict__ x_emb, const float* __restrict__ init_h,
    const float* __restrict__ w1, const float* __restrict__ b1,
    const float* __restrict__ w2, const float* __restrict__ b2,
    const float* __restrict__ w_ih, const float* __restrict__ w_hh,
    const float* __restrict__ b_ih, const float* __restrict__ b_hh,
    const float* __restrict__ bias, const float* __restrict__ out_w,
    float* __restrict__ y_out, float* h_out, int* flags, int* ticket) {
  // LDS ~157 KiB
  __shared__ __align__(16) unsigned char smA[32 * 512];  // A=[ht_prev|h_run] fp16 [32][256], swizzled
  __shared__ float sC[32 * CPAD];
  __shared__ float sHrun[32 * HPAD];
  __shared__ float sHtp[2][32 * HPAD];   // double-buffered ht_prev rows
  __shared__ float sXt[32 * 128];
  __shared__ float sRed[4 * HPAD];
  __shared__ float sV1[128], sV2[128];
  __shared__ float sBias[128], sOutW[128], sB1[128], sB2[128];
  __shared__ unsigned int sMask[128];
  __shared__ int sTicket;

  const int tid = threadIdx.x;
  const int lane = tid & 63;
  const int wv = tid >> 6;        // 0..7
  const int l31 = lane & 31;
  const int lhi = lane >> 5;

  if (tid == 0) sTicket = atomicAdd(ticket, 1);
  __syncthreads();
  const int t = sTicket;

  if (tid < 128) {
    sBias[tid] = bias[tid];
    sOutW[tid] = out_w[tid];
    sB1[tid] = b1[tid];
    sB2[tid] = b2[tid];
    sMask[tid] = 0u;
  }
  for (int i = tid; i < 32 * HPAD; i += 512) sHrun[i] = 0.f;
  __syncthreads();
  if (tid < 32) {
    int qb = qp[tid * TT + t];
    atomicOr(&sMask[qb], 1u << tid);
  }

  const int b = tid >> 4;          // batch 0..31
  const int f = tid & 15;          // 8-float slice
  const unsigned int swzb = (unsigned int)((b & 7) << 4);
  {  // xt rows + zero A right half (h_run = 0)
    int qb = qp[b * TT + t];
    int rb = rp_[b * TT + t];
    const float* src = x_emb + (size_t)(qb + NQl * rb) * HD + f * 8;
    *(f32x4*)(sXt + b * 128 + f * 8) = *(const f32x4*)src;
    *(f32x4*)(sXt + b * 128 + f * 8 + 4) = *(const f32x4*)(src + 4);
    *(uint4*)(smA + b * 512 + ((unsigned int)(256 + f * 16) ^ swzb)) = make_uint4(0, 0, 0, 0);
  }

  // ---- B fragments fp16, resident (24 frags = 96 VGPRs/wave) ----
  const int gcol = wv * 32 + l31;  // r/z column 0..255
  f16x8 Brz[16];
#pragma unroll
  for (int ks = 0; ks < 16; ++ks) {
    const float* src = (ks < 8)
        ? (w_ih + (size_t)gcol * 256 + 128 + ks * 16 + lhi * 8)   // ht half
        : (w_hh + (size_t)gcol * 128 + (ks - 8) * 16 + lhi * 8);  // h_run half
    Brz[ks] = pack_frag_h(*(const f32x4*)src, *(const f32x4*)(src + 4));
  }
  const int ecol = (wv < 4) ? (256 + wv * 32 + l31) : (384 + (wv - 4) * 32 + l31);
  const int erow = (wv < 4) ? ecol : (ecol - 128);  // w_hh row for hn
  f16x8 Bex[8];
#pragma unroll
  for (int ks = 0; ks < 8; ++ks) {
    const float* src = (wv < 4)
        ? (w_ih + (size_t)erow * 256 + 128 + ks * 16 + lhi * 8)  // inn (ht half)
        : (w_hh + (size_t)erow * 128 + ks * 16 + lhi * 8);       // hn (h_run half)
    Bex[ks] = pack_frag_h(*(const f32x4*)src, *(const f32x4*)(src + 4));
  }
  const float brz = b_ih[gcol] + b_hh[gcol];
  const float bex = (wv < 4) ? b_ih[ecol] : b_hh[erow];

  // handoff pointers (32 B slice per thread)
  float* hstore_base = h_out + (((size_t)b * (TT + 1) + (t + 1)) * NQl) * HD + f * 8;
  const float* hload_base = h_out + (((size_t)b * (TT + 1) + t) * NQl) * HD + f * 8;

  // ---- h[:,0,:,:] = init_h broadcast, spread across all 64 WGs (off critical path) ----
  {
    const f32x4* s4 = (const f32x4*)init_h;  // 4096 vec4 per batch
    for (int i = t * 512 + tid; i < 32 * 4096; i += TT * 512) {
      int bb = i >> 12, rem = i & 4095;
      ((f32x4*)(h_out + ((size_t)bb * (TT + 1)) * NQl * HD))[rem] = s4[rem];
    }
  }

  // ---- prologue: ht_prev[:, 0] -> slot 0 ----
  {
    float v[8];
    if (t > 0) {
      if (lane == 0) {
        int c = 0;
        while (flag_read_rmw(&flags[(t - 1) * NQl + 0]) < 8) {
          __builtin_amdgcn_s_sleep(2);
          if (++c > (1 << 20)) break;
        }
      }
      f32x4 a0, a1;
      issue_load32_cc(hload_base, a0, a1);
      wait_vm0_2(a0, a1);
      *(f32x4*)&v[0] = a0; *(f32x4*)&v[4] = a1;
    } else {
      const float* src = init_h + f * 8;
      *(f32x4*)&v[0] = *(const f32x4*)src;
      *(f32x4*)&v[4] = *(const f32x4*)(src + 4);
    }
    *(f32x4*)(sHtp[0] + b * HPAD + f * 8) = *(f32x4*)&v[0];
    *(f32x4*)(sHtp[0] + b * HPAD + f * 8 + 4) = *(f32x4*)&v[4];
    *(uint4*)(smA + b * 512 + ((unsigned int)(f * 16) ^ swzb)) = pack8_h(v);
  }

  const int rowbase = l31 * 512;
  const unsigned int swz = (unsigned int)((l31 & 7) << 4);

  for (int n = 0; n < NQl; ++n) {
    __syncthreads();  // bar A: smA (left-land + right-gates) stable for MFMA

    // ===== MFMA: [32,256] @ [256,512], fp16 single product =====
    CHAIN(16, 0, Brz, brz, gcol)
    if (wv < 4) { CHAIN(8, 0, Bex, bex, ecol) } else { CHAIN(8, 8, Bex, bex, ecol) }
    __syncthreads();  // bar B: sC complete; smA-right free to overwrite

    // ===== poll (RMW) + issue ht_prev[:, n+1] loads; latency hides under MLP+gates =====
    const int nn = n + 1;
    f32x4 p0, p1;
    if (nn < NQl) {
      if (t > 0) {
        if (lane == 0) {
          int c = 0;
          while (flag_read_rmw(&flags[(t - 1) * NQl + nn]) < 8) {
            __builtin_amdgcn_s_sleep(2);
            if (++c > (1 << 20)) break;
          }
        }
        issue_load32_cc(hload_base + (size_t)nn * HD, p0, p1);
      } else {
        const float* src = init_h + (size_t)nn * HD + f * 8;
        p0 = *(const f32x4*)src;
        p1 = *(const f32x4*)(src + 4);
      }
    }

    // ===== MLP correction for matched nodes (fp32, adds to gi cols 0..383) =====
    unsigned int mk = sMask[n];
    while (mk) {
      const int b0 = __ffs(mk) - 1;
      mk &= mk - 1;
      const float* htp_row = sHtp[n & 1] + b0 * HPAD;
      {
        const int j = tid & 127, kq = tid >> 7;
        const float* wr = w1 + (size_t)j * 256 + kq * 64;
        const float* xr = (kq < 2) ? (htp_row + kq * 64)
                                   : (sXt + b0 * 128 + (kq - 2) * 64);
        float s = 0.f;
#pragma unroll
        for (int ii = 0; ii < 16; ++ii)
          s += dot4_(*(const f32x4*)(wr + ii * 4), *(const f32x4*)(xr + ii * 4));
        sRed[kq * HPAD + j] = s;
      }
      __syncthreads();
      if (tid < 128) {
        float v = sB1[tid] + sRed[tid] + sRed[HPAD + tid] + sRed[2 * HPAD + tid] +
                  sRed[3 * HPAD + tid];
        sV1[tid] = fmaxf(v, 0.f);
      }
      __syncthreads();
      {
        const int j = tid & 127, kq = tid >> 7;
        const float* wr = w2 + (size_t)j * 128 + kq * 32;
        const float* xr = sV1 + kq * 32;
        float s = 0.f;
#pragma unroll
        for (int ii = 0; ii < 8; ++ii)
          s += dot4_(*(const f32x4*)(wr + ii * 4), *(const f32x4*)(xr + ii * 4));
        sRed[kq * HPAD + j] = s;
      }
      __syncthreads();
      if (tid < 128)
        sV2[tid] = sB2[tid] + sRed[tid] + sRed[HPAD + tid] + sRed[2 * HPAD + tid] +
                   sRed[3 * HPAD + tid];
      __syncthreads();
      if (tid < 384) {
        const float* wr = w_ih + (size_t)tid * 256;  // m-columns (first 128)
        float s = 0.f;
#pragma unroll
        for (int ii = 0; ii < 32; ++ii)
          s += dot4_(*(const f32x4*)(wr + ii * 4), *(const f32x4*)(sV2 + ii * 4));
        sC[b0 * CPAD + tid] += s;
      }
      __syncthreads();
    }

    // ===== gates (fp32): 8 h-elems per thread =====
    float yp = 0.f;
    {
      const int j0 = f * 8;
      const float* Cb = sC + b * CPAD;
      float rpre[8], zpre[8], ipre[8], hpre[8], hold[8];
      *(f32x4*)&rpre[0] = *(const f32x4*)(Cb + j0);
      *(f32x4*)&rpre[4] = *(const f32x4*)(Cb + j0 + 4);
      *(f32x4*)&zpre[0] = *(const f32x4*)(Cb + 128 + j0);
      *(f32x4*)&zpre[4] = *(const f32x4*)(Cb + 128 + j0 + 4);
      *(f32x4*)&ipre[0] = *(const f32x4*)(Cb + 256 + j0);
      *(f32x4*)&ipre[4] = *(const f32x4*)(Cb + 256 + j0 + 4);
      *(f32x4*)&hpre[0] = *(const f32x4*)(Cb + 384 + j0);
      *(f32x4*)&hpre[4] = *(const f32x4*)(Cb + 384 + j0 + 4);
      *(f32x4*)&hold[0] = *(const f32x4*)(sHrun + b * HPAD + j0);
      *(f32x4*)&hold[4] = *(const f32x4*)(sHrun + b * HPAD + j0 + 4);
      float hnew[8];
#pragma unroll
      for (int i = 0; i < 8; ++i) {
        float rg = sigmoidf_(rpre[i]);
        float zg = sigmoidf_(zpre[i]);
        float ng = tanhf_(ipre[i] + rg * hpre[i]);
        float hv = ng + zg * (hold[i] - ng);
        hnew[i] = hv;
        yp += hv * sOutW[j0 + i];
      }
      *(f32x4*)(sHrun + b * HPAD + j0) = *(f32x4*)&hnew[0];
      *(f32x4*)(sHrun + b * HPAD + j0 + 4) = *(f32x4*)&hnew[4];
      *(uint4*)(smA + b * 512 + ((unsigned int)(256 + f * 16) ^ swzb)) = pack8_h(hnew);
      store32_cc(hstore_base + (size_t)n * HD, *(f32x4*)&hnew[0], *(f32x4*)&hnew[4]);
    }

    // ===== per-wave drain + flag add (no block barrier on the handoff path) =====
    if (nn < NQl && t > 0) {
      wait_vm0_2(p0, p1);   // drains h-stores AND ties prefetch regs (rule #18)
    } else {
      asm volatile("s_waitcnt vmcnt(0)" ::: "memory");
    }
    if (lane == 0) flag_add1(&flags[t * NQl + n]);

    // ===== land prefetched row n+1 (slot nn&1) + deferred y store =====
    if (nn < NQl) {
      float v[8];
      *(f32x4*)&v[0] = p0; *(f32x4*)&v[4] = p1;
      *(f32x4*)(sHtp[nn & 1] + b * HPAD + f * 8) = p0;
      *(f32x4*)(sHtp[nn & 1] + b * HPAD + f * 8 + 4) = p1;
      *(uint4*)(smA + b * 512 + ((unsigned int)(f * 16) ^ swzb)) = pack8_h(v);
    }
    yp += __shfl_xor(yp, 1);
    yp += __shfl_xor(yp, 2);
    yp += __shfl_xor(yp, 4);
    yp += __shfl_xor(yp, 8);
    if (f == 0) {
      float yv = sigmoidf_(yp + sBias[n]);
      y_out[((size_t)b * TT + t) * NQl + n] = yv;
    }
  }
}

extern "C" void kernel_launch(void* const* d_in, const int* in_sizes, int n_in,
                              void* d_out, int out_size, void* d_ws, size_t ws_size,
                              hipStream_t stream) {
  (void)in_sizes; (void)n_in; (void)out_size; (void)ws_size;
  const int* q = (const int*)d_in[0];
  const int* r = (const int*)d_in[1];
  const float* x_emb = (const float*)d_in[2];
  // d_in[3] = q_emb: provably unused (only feeds masked-out MLP rows)
  const float* init_h = (const float*)d_in[4];
  const float* w1 = (const float*)d_in[5];
  const float* b1 = (const float*)d_in[6];
  const float* w2 = (const float*)d_in[7];
  const float* b2 = (const float*)d_in[8];
  const float* w_ih = (const float*)d_in[9];
  const float* w_hh = (const float*)d_in[10];
  const float* b_ih = (const float*)d_in[11];
  const float* b_hh = (const float*)d_in[12];
  const float* bias = (const float*)d_in[13];
  const float* out_w = (const float*)d_in[14];

  float* y_out = (float*)d_out;
  float* h_out = y_out + (size_t)BB * TT * NQl;  // y first, then h
  int* flags = (int*)d_ws;
  int* ticket = flags + TT * NQl;

  hipMemsetAsync(d_ws, 0, (TT * NQl + 16) * sizeof(int), stream);
  gkt_wavefront<<<TT, 512, 0, stream>>>(q, r, x_emb, init_h, w1, b1, w2, b2,
                                        w_ih, w_hh, b_ih, b_hh, bias, out_w,
                                        y_out, h_out, flags, ticket);
}

// Round 7
// 2478.410 us; speedup vs baseline: 1.2305x; 1.2305x over previous
//
#include <hip/hip_runtime.h>

#define BB 32
#define TT 64
#define NQl 128
#define HD 128
#define CPAD 524   // sC row stride (floats)
#define HPAD 132   // padded row stride for fp32 [32][128] tiles

typedef _Float16 f16x8 __attribute__((ext_vector_type(8)));
typedef float f32x16 __attribute__((ext_vector_type(16)));
typedef float f32x4 __attribute__((ext_vector_type(4)));

__device__ __forceinline__ float sigmoidf_(float x) {
  return __builtin_amdgcn_rcpf(1.f + __expf(-x));
}
__device__ __forceinline__ float tanhf_(float x) {
  float a = fminf(fabsf(x), 15.f);
  float e = __expf(-2.f * a);
  float t = (1.f - e) * __builtin_amdgcn_rcpf(1.f + e);
  return copysignf(t, x);
}
__device__ __forceinline__ float dot4_(f32x4 a, f32x4 b) {
  return a[0] * b[0] + a[1] * b[1] + a[2] * b[2] + a[3] * b[3];
}
__device__ __forceinline__ f16x8 pack_frag_h(f32x4 a, f32x4 b) {
  f16x8 o;
  o[0] = (_Float16)a[0]; o[1] = (_Float16)a[1];
  o[2] = (_Float16)a[2]; o[3] = (_Float16)a[3];
  o[4] = (_Float16)b[0]; o[5] = (_Float16)b[1];
  o[6] = (_Float16)b[2]; o[7] = (_Float16)b[3];
  return o;
}
__device__ __forceinline__ uint4 pack8_h(const float v[8]) {
  union { f16x8 h; uint4 u; } c;
#pragma unroll
  for (int i = 0; i < 8; ++i) c.h[i] = (_Float16)v[i];
  return c.u;
}

// ---- agent-coherent (sc1: coherence point, cross-XCD) wide loads/stores ----
__device__ __forceinline__ void issue_load32_cc(const float* p, f32x4& a, f32x4& b) {
  asm volatile(
      "global_load_dwordx4 %0, %2, off sc1\n\t"
      "global_load_dwordx4 %1, %2, off offset:16 sc1"
      : "=&v"(a), "=&v"(b) : "v"(p) : "memory");
}
__device__ __forceinline__ void wait_vm0_2(f32x4& a, f32x4& b) {
  asm volatile("s_waitcnt vmcnt(0)" : "+v"(a), "+v"(b) :: "memory");
  __builtin_amdgcn_sched_barrier(0);
}
__device__ __forceinline__ void store32_cc(float* p, f32x4 a, f32x4 b) {
  asm volatile(
      "global_store_dwordx4 %0, %1, off sc1\n\t"
      "global_store_dwordx4 %0, %2, off offset:16 sc1"
      :: "v"(p), "v"(a), "v"(b) : "memory");
}

// RMW-based flag ops: always execute at the coherence point (no stale-cache path)
__device__ __forceinline__ int flag_read_rmw(int* p) {
  return __hip_atomic_fetch_add(p, 0, __ATOMIC_RELAXED, __HIP_MEMORY_SCOPE_AGENT);
}
__device__ __forceinline__ void flag_add1(int* p) {
  __hip_atomic_fetch_add(p, 1, __ATOMIC_RELAXED, __HIP_MEMORY_SCOPE_AGENT);
}

// fp16 single-product MFMA chain over NS K-slots starting at S0 -> sC[:, OUTCOL]
#define CHAIN(NS, S0, FR, BIASV, OUTCOL)                                        \
  {                                                                             \
    f32x16 acc;                                                                 \
    _Pragma("unroll")                                                           \
    for (int i = 0; i < 16; ++i) acc[i] = (BIASV);                              \
    _Pragma("unroll")                                                           \
    for (int ks = 0; ks < (NS); ++ks) {                                         \
      unsigned int off = ((unsigned int)(((S0) + ks) * 32 + (lhi << 4))) ^ swz; \
      f16x8 av = *(const f16x8*)(smA + rowbase + off);                          \
      acc = __builtin_amdgcn_mfma_f32_32x32x16_f16(av, FR[ks], acc, 0, 0, 0);   \
    }                                                                           \
    _Pragma("unroll")                                                           \
    for (int rg = 0; rg < 16; ++rg) {                                           \
      int br = (rg & 3) + 8 * (rg >> 2) + 4 * lhi;                              \
      sC[br * CPAD + (OUTCOL)] = acc[rg];                                       \
    }                                                                           \
  }

// One workgroup (512 threads = 8 waves) per time step t.
// Wavefront pipeline: step (t,n) consumes flag-counter(t-1,n)==8; depth T+NQ-1.
// KEY ORDERING: own flag(t,n) is set BEFORE polling flag(t-1,n+1) — the flag
// chains of consecutive generations are decoupled (R6 had them serialized).
__global__ void __launch_bounds__(512, 2) gkt_wavefront(
    const int* __restrict__ qp, const int* __restrict__ rp_,
    const float* __restrict__ x_emb, const float* __restrict__ init_h,
    const float* __restrict__ w1, const float* __restrict__ b1,
    const float* __restrict__ w2, const float* __restrict__ b2,
    const float* __restrict__ w_ih, const float* __restrict__ w_hh,
    const float* __restrict__ b_ih, const float* __restrict__ b_hh,
    const float* __restrict__ bias, const float* __restrict__ out_w,
    float* __restrict__ y_out, float* h_out, int* flags, int* ticket) {
  // LDS ~157 KiB
  __shared__ __align__(16) unsigned char smA[32 * 512];  // A=[ht_prev|h_run] fp16 [32][256], swizzled
  __shared__ float sC[32 * CPAD];
  __shared__ float sHrun[32 * HPAD];
  __shared__ float sHtp[2][32 * HPAD];   // double-buffered ht_prev rows
  __shared__ float sXt[32 * 128];
  __shared__ float sRed[4 * HPAD];
  __shared__ float sV1[128], sV2[128];
  __shared__ float sBias[128], sOutW[128], sB1[128], sB2[128];
  __shared__ unsigned int sMask[128];
  __shared__ int sTicket;

  const int tid = threadIdx.x;
  const int lane = tid & 63;
  const int wv = tid >> 6;        // 0..7
  const int l31 = lane & 31;
  const int lhi = lane >> 5;

  if (tid == 0) sTicket = atomicAdd(ticket, 1);
  __syncthreads();
  const int t = sTicket;

  if (tid < 128) {
    sBias[tid] = bias[tid];
    sOutW[tid] = out_w[tid];
    sB1[tid] = b1[tid];
    sB2[tid] = b2[tid];
    sMask[tid] = 0u;
  }
  for (int i = tid; i < 32 * HPAD; i += 512) sHrun[i] = 0.f;
  __syncthreads();
  if (tid < 32) {
    int qb = qp[tid * TT + t];
    atomicOr(&sMask[qb], 1u << tid);
  }

  const int b = tid >> 4;          // batch 0..31
  const int f = tid & 15;          // 8-float slice
  const unsigned int swzb = (unsigned int)((b & 7) << 4);
  {  // xt rows + zero A right half (h_run = 0)
    int qb = qp[b * TT + t];
    int rb = rp_[b * TT + t];
    const float* src = x_emb + (size_t)(qb + NQl * rb) * HD + f * 8;
    *(f32x4*)(sXt + b * 128 + f * 8) = *(const f32x4*)src;
    *(f32x4*)(sXt + b * 128 + f * 8 + 4) = *(const f32x4*)(src + 4);
    *(uint4*)(smA + b * 512 + ((unsigned int)(256 + f * 16) ^ swzb)) = make_uint4(0, 0, 0, 0);
  }

  // ---- B fragments fp16, resident (24 frags = 96 VGPRs/wave) ----
  const int gcol = wv * 32 + l31;  // r/z column 0..255
  f16x8 Brz[16];
#pragma unroll
  for (int ks = 0; ks < 16; ++ks) {
    const float* src = (ks < 8)
        ? (w_ih + (size_t)gcol * 256 + 128 + ks * 16 + lhi * 8)   // ht half
        : (w_hh + (size_t)gcol * 128 + (ks - 8) * 16 + lhi * 8);  // h_run half
    Brz[ks] = pack_frag_h(*(const f32x4*)src, *(const f32x4*)(src + 4));
  }
  const int ecol = (wv < 4) ? (256 + wv * 32 + l31) : (384 + (wv - 4) * 32 + l31);
  const int erow = (wv < 4) ? ecol : (ecol - 128);  // w_hh row for hn
  f16x8 Bex[8];
#pragma unroll
  for (int ks = 0; ks < 8; ++ks) {
    const float* src = (wv < 4)
        ? (w_ih + (size_t)erow * 256 + 128 + ks * 16 + lhi * 8)  // inn (ht half)
        : (w_hh + (size_t)erow * 128 + ks * 16 + lhi * 8);       // hn (h_run half)
    Bex[ks] = pack_frag_h(*(const f32x4*)src, *(const f32x4*)(src + 4));
  }
  const float brz = b_ih[gcol] + b_hh[gcol];
  const float bex = (wv < 4) ? b_ih[ecol] : b_hh[erow];

  // handoff pointers (32 B slice per thread)
  float* hstore_base = h_out + (((size_t)b * (TT + 1) + (t + 1)) * NQl) * HD + f * 8;
  const float* hload_base = h_out + (((size_t)b * (TT + 1) + t) * NQl) * HD + f * 8;

  // ---- h[:,0,:,:] = init_h broadcast, spread across all 64 WGs (off critical path) ----
  {
    const f32x4* s4 = (const f32x4*)init_h;  // 4096 vec4 per batch
    for (int i = t * 512 + tid; i < 32 * 4096; i += TT * 512) {
      int bb = i >> 12, rem = i & 4095;
      ((f32x4*)(h_out + ((size_t)bb * (TT + 1)) * NQl * HD))[rem] = s4[rem];
    }
  }

  // ---- prologue: ht_prev[:, 0] -> slot 0 ----
  {
    float v[8];
    if (t > 0) {
      if (lane == 0) {
        int c = 0;
        while (flag_read_rmw(&flags[(t - 1) * NQl + 0]) < 8) {
          __builtin_amdgcn_s_sleep(2);
          if (++c > (1 << 20)) break;
        }
      }
      f32x4 a0, a1;
      issue_load32_cc(hload_base, a0, a1);
      wait_vm0_2(a0, a1);
      *(f32x4*)&v[0] = a0; *(f32x4*)&v[4] = a1;
    } else {
      const float* src = init_h + f * 8;
      *(f32x4*)&v[0] = *(const f32x4*)src;
      *(f32x4*)&v[4] = *(const f32x4*)(src + 4);
    }
    *(f32x4*)(sHtp[0] + b * HPAD + f * 8) = *(f32x4*)&v[0];
    *(f32x4*)(sHtp[0] + b * HPAD + f * 8 + 4) = *(f32x4*)&v[4];
    *(uint4*)(smA + b * 512 + ((unsigned int)(f * 16) ^ swzb)) = pack8_h(v);
  }

  const int rowbase = l31 * 512;
  const unsigned int swz = (unsigned int)((l31 & 7) << 4);

  for (int n = 0; n < NQl; ++n) {
    __syncthreads();  // bar A: smA (left-land + right-gates) stable for MFMA

    // ===== MFMA: [32,256] @ [256,512], fp16 single product =====
    CHAIN(16, 0, Brz, brz, gcol)
    if (wv < 4) { CHAIN(8, 0, Bex, bex, ecol) } else { CHAIN(8, 8, Bex, bex, ecol) }
    __syncthreads();  // bar B: sC complete; smA-right free to overwrite

    // ===== MLP correction for matched nodes (fp32, adds to gi cols 0..383) =====
    unsigned int mk = sMask[n];
    while (mk) {
      const int b0 = __ffs(mk) - 1;
      mk &= mk - 1;
      const float* htp_row = sHtp[n & 1] + b0 * HPAD;
      {
        const int j = tid & 127, kq = tid >> 7;
        const float* wr = w1 + (size_t)j * 256 + kq * 64;
        const float* xr = (kq < 2) ? (htp_row + kq * 64)
                                   : (sXt + b0 * 128 + (kq - 2) * 64);
        float s = 0.f;
#pragma unroll
        for (int ii = 0; ii < 16; ++ii)
          s += dot4_(*(const f32x4*)(wr + ii * 4), *(const f32x4*)(xr + ii * 4));
        sRed[kq * HPAD + j] = s;
      }
      __syncthreads();
      if (tid < 128) {
        float v = sB1[tid] + sRed[tid] + sRed[HPAD + tid] + sRed[2 * HPAD + tid] +
                  sRed[3 * HPAD + tid];
        sV1[tid] = fmaxf(v, 0.f);
      }
      __syncthreads();
      {
        const int j = tid & 127, kq = tid >> 7;
        const float* wr = w2 + (size_t)j * 128 + kq * 32;
        const float* xr = sV1 + kq * 32;
        float s = 0.f;
#pragma unroll
        for (int ii = 0; ii < 8; ++ii)
          s += dot4_(*(const f32x4*)(wr + ii * 4), *(const f32x4*)(xr + ii * 4));
        sRed[kq * HPAD + j] = s;
      }
      __syncthreads();
      if (tid < 128)
        sV2[tid] = sB2[tid] + sRed[tid] + sRed[HPAD + tid] + sRed[2 * HPAD + tid] +
                   sRed[3 * HPAD + tid];
      __syncthreads();
      if (tid < 384) {
        const float* wr = w_ih + (size_t)tid * 256;  // m-columns (first 128)
        float s = 0.f;
#pragma unroll
        for (int ii = 0; ii < 32; ++ii)
          s += dot4_(*(const f32x4*)(wr + ii * 4), *(const f32x4*)(sV2 + ii * 4));
        sC[b0 * CPAD + tid] += s;
      }
      __syncthreads();
    }

    // ===== gates (fp32): 8 h-elems per thread =====
    float yp = 0.f;
    {
      const int j0 = f * 8;
      const float* Cb = sC + b * CPAD;
      float rpre[8], zpre[8], ipre[8], hpre[8], hold[8];
      *(f32x4*)&rpre[0] = *(const f32x4*)(Cb + j0);
      *(f32x4*)&rpre[4] = *(const f32x4*)(Cb + j0 + 4);
      *(f32x4*)&zpre[0] = *(const f32x4*)(Cb + 128 + j0);
      *(f32x4*)&zpre[4] = *(const f32x4*)(Cb + 128 + j0 + 4);
      *(f32x4*)&ipre[0] = *(const f32x4*)(Cb + 256 + j0);
      *(f32x4*)&ipre[4] = *(const f32x4*)(Cb + 256 + j0 + 4);
      *(f32x4*)&hpre[0] = *(const f32x4*)(Cb + 384 + j0);
      *(f32x4*)&hpre[4] = *(const f32x4*)(Cb + 384 + j0 + 4);
      *(f32x4*)&hold[0] = *(const f32x4*)(sHrun + b * HPAD + j0);
      *(f32x4*)&hold[4] = *(const f32x4*)(sHrun + b * HPAD + j0 + 4);
      float hnew[8];
#pragma unroll
      for (int i = 0; i < 8; ++i) {
        float rg = sigmoidf_(rpre[i]);
        float zg = sigmoidf_(zpre[i]);
        float ng = tanhf_(ipre[i] + rg * hpre[i]);
        float hv = ng + zg * (hold[i] - ng);
        hnew[i] = hv;
        yp += hv * sOutW[j0 + i];
      }
      *(f32x4*)(sHrun + b * HPAD + j0) = *(f32x4*)&hnew[0];
      *(f32x4*)(sHrun + b * HPAD + j0 + 4) = *(f32x4*)&hnew[4];
      *(uint4*)(smA + b * 512 + ((unsigned int)(256 + f * 16) ^ swzb)) = pack8_h(hnew);
      store32_cc(hstore_base + (size_t)n * HD, *(f32x4*)&hnew[0], *(f32x4*)&hnew[4]);
    }

    // ===== per-wave: drain own h-stores, then set OWN flag (before any polling) =====
    asm volatile("s_waitcnt vmcnt(0)" ::: "memory");
    if (lane == 0) flag_add1(&flags[t * NQl + n]);

    // ===== per-wave: poll parent flag(n+1), fetch + land row n+1 =====
    const int nn = n + 1;
    if (nn < NQl) {
      f32x4 p0, p1;
      if (t > 0) {
        if (lane == 0) {
          int c = 0;
          while (flag_read_rmw(&flags[(t - 1) * NQl + nn]) < 8) {
            __builtin_amdgcn_s_sleep(2);
            if (++c > (1 << 20)) break;
          }
        }
        issue_load32_cc(hload_base + (size_t)nn * HD, p0, p1);
        wait_vm0_2(p0, p1);
      } else {
        const float* src = init_h + (size_t)nn * HD + f * 8;
        p0 = *(const f32x4*)src;
        p1 = *(const f32x4*)(src + 4);
      }
      float v[8];
      *(f32x4*)&v[0] = p0; *(f32x4*)&v[4] = p1;
      *(f32x4*)(sHtp[nn & 1] + b * HPAD + f * 8) = p0;
      *(f32x4*)(sHtp[nn & 1] + b * HPAD + f * 8 + 4) = p1;
      *(uint4*)(smA + b * 512 + ((unsigned int)(f * 16) ^ swzb)) = pack8_h(v);
    }

    // ===== deferred y store (off handoff path) =====
    yp += __shfl_xor(yp, 1);
    yp += __shfl_xor(yp, 2);
    yp += __shfl_xor(yp, 4);
    yp += __shfl_xor(yp, 8);
    if (f == 0) {
      float yv = sigmoidf_(yp + sBias[n]);
      y_out[((size_t)b * TT + t) * NQl + n] = yv;
    }
  }
}

extern "C" void kernel_launch(void* const* d_in, const int* in_sizes, int n_in,
                              void* d_out, int out_size, void* d_ws, size_t ws_size,
                              hipStream_t stream) {
  (void)in_sizes; (void)n_in; (void)out_size; (void)ws_size;
  const int* q = (const int*)d_in[0];
  const int* r = (const int*)d_in[1];
  const float* x_emb = (const float*)d_in[2];
  // d_in[3] = q_emb: provably unused (only feeds masked-out MLP rows)
  const float* init_h = (const float*)d_in[4];
  const float* w1 = (const float*)d_in[5];
  const float* b1 = (const float*)d_in[6];
  const float* w2 = (const float*)d_in[7];
  const float* b2 = (const float*)d_in[8];
  const float* w_ih = (const float*)d_in[9];
  const float* w_hh = (const float*)d_in[10];
  const float* b_ih = (const float*)d_in[11];
  const float* b_hh = (const float*)d_in[12];
  const float* bias = (const float*)d_in[13];
  const float* out_w = (const float*)d_in[14];

  float* y_out = (float*)d_out;
  float* h_out = y_out + (size_t)BB * TT * NQl;  // y first, then h
  int* flags = (int*)d_ws;
  int* ticket = flags + TT * NQl;

  hipMemsetAsync(d_ws, 0, (TT * NQl + 16) * sizeof(int), stream);
  gkt_wavefront<<<TT, 512, 0, stream>>>(q, r, x_emb, init_h, w1, b1, w2, b2,
                                        w_ih, w_hh, b_ih, b_hh, bias, out_w,
                                        y_out, h_out, flags, ticket);
}